// Round 1
// baseline (4460.551 us; speedup 1.0000x reference)
//
#include <hip/hip_runtime.h>
#include <cstdint>
#include <cstddef>

#define BB 8
#define CC 64
#define NN 4096
#define OO 64
#define KK 20
#define TWO_C 128

#define KM 16      // rows per knn block
#define KT 512     // j-tile width
#define KBW 536    // buffer width: 512 tile + 20 appended + pad

// ---------------- kernel 1: squared norms xx[b,n] ----------------
__global__ __launch_bounds__(256) void xx_kernel(const float* __restrict__ x,
                                                 float* __restrict__ xx) {
    int t = blockIdx.x * 256 + threadIdx.x;  // [0, B*N)
    int b = t >> 12, n = t & (NN - 1);
    const float* xp = x + (size_t)b * CC * NN + n;
    float acc = 0.f;
#pragma unroll
    for (int c = 0; c < CC; ++c) {
        float v = xp[(size_t)c * NN];
        acc += v * v;
    }
    xx[t] = acc;
}

// ---------------- kernel 2: kNN (top-K of neg squared distance) ----------------
// grid (N/KM, B), block 256. dist(i,j) = 2*<xi,xj> - xx_i - xx_j, top-20 per row,
// tie-break: lower j wins (matches lax.top_k set semantics).
__global__ __launch_bounds__(256) void knn_kernel(const float* __restrict__ x,
                                                  const float* __restrict__ xx,
                                                  int* __restrict__ idx_out) {
    __shared__ float xiT[CC][KM];     // center features, c-major for float4 reads
    __shared__ float xxi[KM];
    __shared__ float buf[KM][KBW];    // per-row distances + appended running top
    __shared__ float topv[KM][KK];
    __shared__ int   topi[KM][KK];
    __shared__ int   api[KM][KK];     // indices of appended entries

    const int tid = threadIdx.x;
    const int b = blockIdx.y;
    const int i0 = blockIdx.x * KM;
    const float* xb = x + (size_t)b * CC * NN;

    for (int e = tid; e < KM * CC; e += 256) {
        int m = e & (KM - 1), c = e >> 4;
        xiT[c][m] = xb[(size_t)c * NN + i0 + m];
    }
    if (tid < KM) xxi[tid] = xx[b * NN + i0 + tid];
    for (int e = tid; e < KM * KK; e += 256) {
        int m = e / KK, k = e - m * KK;
        topv[m][k] = -__builtin_inff();
        topi[m][k] = 0;
    }
    __syncthreads();

    for (int jt = 0; jt < NN / KT; ++jt) {
        const int j0 = jt * KT;
        // ---- phase A: distances for this j-tile (register-blocked over KM rows)
#pragma unroll
        for (int rep = 0; rep < KT / 256; ++rep) {
            const int jl = rep * 256 + tid;
            const int j = j0 + jl;
            float acc[KM];
#pragma unroll
            for (int m = 0; m < KM; ++m) acc[m] = 0.f;
            const float* xp = xb + j;
            float xxj = xx[b * NN + j];
#pragma unroll 8
            for (int c = 0; c < CC; ++c) {
                float xv = xp[(size_t)c * NN];
                const float4* xr = (const float4*)&xiT[c][0];
                float4 a0 = xr[0], a1 = xr[1], a2 = xr[2], a3 = xr[3];
                acc[0]  += xv * a0.x;  acc[1]  += xv * a0.y;
                acc[2]  += xv * a0.z;  acc[3]  += xv * a0.w;
                acc[4]  += xv * a1.x;  acc[5]  += xv * a1.y;
                acc[6]  += xv * a1.z;  acc[7]  += xv * a1.w;
                acc[8]  += xv * a2.x;  acc[9]  += xv * a2.y;
                acc[10] += xv * a2.z;  acc[11] += xv * a2.w;
                acc[12] += xv * a3.x;  acc[13] += xv * a3.y;
                acc[14] += xv * a3.z;  acc[15] += xv * a3.w;
            }
#pragma unroll
            for (int m = 0; m < KM; ++m)
                buf[m][jl] = 2.f * acc[m] - xxi[m] - xxj;
        }
        // append current running top-K as extra candidates
        for (int e = tid; e < KM * KK; e += 256) {
            int m = e / KK, k = e - m * KK;
            buf[m][KT + k] = topv[m][k];
            api[m][k] = topi[m][k];
        }
        __syncthreads();

        // ---- phase B: iterative argmax selection; each wave owns KM/4 rows
        const int wave = tid >> 6, lane = tid & 63;
        for (int r = 0; r < KM / 4; ++r) {
            const int m = wave * (KM / 4) + r;
            for (int ks = 0; ks < KK; ++ks) {
                float best = -__builtin_inff();
                int bgi = 0x7fffffff;
                int bpos = 0;
                for (int e = lane; e < KT + KK; e += 64) {
                    float v = buf[m][e];
                    int gi = (e < KT) ? (j0 + e) : api[m][e - KT];
                    if (v > best || (v == best && gi < bgi)) { best = v; bgi = gi; bpos = e; }
                }
#pragma unroll
                for (int off = 32; off > 0; off >>= 1) {
                    float ov = __shfl_xor(best, off, 64);
                    int ogi = __shfl_xor(bgi, off, 64);
                    int ope = __shfl_xor(bpos, off, 64);
                    if (ov > best || (ov == best && ogi < bgi)) { best = ov; bgi = ogi; bpos = ope; }
                }
                if (lane == 0) { topv[m][ks] = best; topi[m][ks] = bgi; }
                // all lanes agree on bpos; same-address same-value write, then in-order DS
                buf[m][bpos] = -__builtin_inff();
                __builtin_amdgcn_wave_barrier();
            }
        }
        __syncthreads();
    }

    for (int e = tid; e < KM * KK; e += 256) {
        int m = e / KK, k = e - m * KK;
        idx_out[((size_t)b * NN + i0 + m) * KK + k] = topi[m][k];
    }
}

// ---------------- kernel 3: P = xt*W1^T, D = xt*(W2-W1)^T ----------------
// grid (N/256, B, 2): z = o-half (32 channels). block 256 = one thread per n.
__global__ __launch_bounds__(256) void pd_kernel(const float* __restrict__ x,
                                                 const float* __restrict__ W,
                                                 float* __restrict__ P,
                                                 float* __restrict__ Dd) {
    __shared__ float w1T[CC][32];
    __shared__ float wdT[CC][32];
    const int tid = threadIdx.x;
    const int b = blockIdx.y;
    const int o0 = blockIdx.z * 32;
    for (int e = tid; e < 32 * CC; e += 256) {
        int ol = e >> 6, c = e & 63;
        float w1 = W[(o0 + ol) * TWO_C + c];
        float w2 = W[(o0 + ol) * TWO_C + CC + c];
        w1T[c][ol] = w1;
        wdT[c][ol] = w2 - w1;
    }
    __syncthreads();
    const int n = blockIdx.x * 256 + tid;
    float accp[32], accd[32];
#pragma unroll
    for (int i = 0; i < 32; ++i) { accp[i] = 0.f; accd[i] = 0.f; }
    const float* xp = x + (size_t)b * CC * NN + n;
    for (int c = 0; c < CC; ++c) {
        float xv = xp[(size_t)c * NN];
        const float4* w1r = (const float4*)&w1T[c][0];
        const float4* wdr = (const float4*)&wdT[c][0];
#pragma unroll
        for (int g = 0; g < 8; ++g) {
            float4 aw = w1r[g]; float4 bw = wdr[g];
            accp[4*g+0] += xv * aw.x; accp[4*g+1] += xv * aw.y;
            accp[4*g+2] += xv * aw.z; accp[4*g+3] += xv * aw.w;
            accd[4*g+0] += xv * bw.x; accd[4*g+1] += xv * bw.y;
            accd[4*g+2] += xv * bw.z; accd[4*g+3] += xv * bw.w;
        }
    }
    size_t base = ((size_t)b * NN + n) * OO + o0;
#pragma unroll
    for (int g = 0; g < 8; ++g) {
        *(float4*)&P[base + 4*g*1]  = make_float4(accp[4*g], accp[4*g+1], accp[4*g+2], accp[4*g+3]);
        *(float4*)&Dd[base + 4*g*1] = make_float4(accd[4*g], accd[4*g+1], accd[4*g+2], accd[4*g+3]);
    }
}

// ---------------- kernel 4: BN batch stats (sum, sumsq) per channel ----------------
// grid (B*N/128), block 256 = 4 row-groups x 64 channels.
__global__ __launch_bounds__(256) void stats_kernel(const float* __restrict__ P,
                                                    const float* __restrict__ Dd,
                                                    const int* __restrict__ idx,
                                                    double* __restrict__ sums) {
    const int tid = threadIdx.x;
    const int o = tid & 63, g = tid >> 6;
    const int row0 = blockIdx.x * 128;
    double s1 = 0.0, s2 = 0.0;
    for (int i = 0; i < 32; ++i) {
        int row = row0 + g + 4 * i;
        int b = row >> 12;
        float d = Dd[(size_t)row * OO + o];
        const int* ip = idx + (size_t)row * KK;
        const float* Pb = P + ((size_t)b * NN) * OO;
#pragma unroll
        for (int k = 0; k < KK; ++k) {
            int j = ip[k];
            float y = Pb[(size_t)j * OO + o] + d;
            s1 += (double)y;
            s2 += (double)y * (double)y;
        }
    }
    __shared__ double r1[4][64];
    __shared__ double r2[4][64];
    r1[g][o] = s1; r2[g][o] = s2;
    __syncthreads();
    if (g == 0) {
        double a1 = r1[0][o] + r1[1][o] + r1[2][o] + r1[3][o];
        double a2 = r2[0][o] + r2[1][o] + r2[2][o] + r2[3][o];
        atomicAdd(&sums[o], a1);
        atomicAdd(&sums[64 + o], a2);
    }
}

// ---------------- kernel 5: finalize scale/shift ----------------
__global__ void finalize_kernel(const double* __restrict__ sums,
                                const float* __restrict__ gamma,
                                const float* __restrict__ beta,
                                float* __restrict__ ss) {
    int o = threadIdx.x;  // 64 threads
    const double cnt = (double)BB * NN * KK;
    double mean = sums[o] / cnt;
    double var = sums[64 + o] / cnt - mean * mean;
    double rs = 1.0 / sqrt(var + 1e-5);
    double sc = (double)gamma[o] * rs;
    ss[o] = (float)sc;
    ss[64 + o] = (float)((double)beta[o] - mean * sc);
}

// ---------------- kernel 6: gather + BN affine + LeakyReLU + max_k + transpose ----------------
// grid (N/64, B), block 256 = 4 row-groups x 64 channels.
__global__ __launch_bounds__(256) void out_kernel(const float* __restrict__ P,
                                                  const float* __restrict__ Dd,
                                                  const int* __restrict__ idx,
                                                  const float* __restrict__ ss,
                                                  float* __restrict__ out) {
    __shared__ float tile[64][65];
    const int tid = threadIdx.x;
    const int o = tid & 63, g = tid >> 6;
    const int b = blockIdx.y;
    const int n0 = blockIdx.x * 64;
    const float sc = ss[o], sh = ss[64 + o];
    const float* Pb = P + ((size_t)b * NN) * OO;
    for (int i = 0; i < 16; ++i) {
        int nl = g + 4 * i;
        int row = b * NN + n0 + nl;
        float d = Dd[(size_t)row * OO + o];
        const int* ip = idx + (size_t)row * KK;
        float mv = -__builtin_inff();
#pragma unroll
        for (int k = 0; k < KK; ++k) {
            int j = ip[k];
            float y = Pb[(size_t)j * OO + o] + d;
            float t = y * sc + sh;
            t = (t >= 0.f) ? t : 0.2f * t;
            mv = fmaxf(mv, t);
        }
        tile[nl][o] = mv;
    }
    __syncthreads();
    for (int i = 0; i < 16; ++i) {
        int oo = g + 4 * i;
        out[((size_t)b * OO + oo) * NN + n0 + o] = tile[o][oo];
    }
}

// ---------------- launch ----------------
extern "C" void kernel_launch(void* const* d_in, const int* in_sizes, int n_in,
                              void* d_out, int out_size, void* d_ws, size_t ws_size,
                              hipStream_t stream) {
    (void)in_sizes; (void)n_in; (void)out_size; (void)ws_size;
    const float* x     = (const float*)d_in[0];   // [B, C, N]
    const float* W     = (const float*)d_in[1];   // [O, 2C]
    const float* gamma = (const float*)d_in[2];   // [O]
    const float* beta  = (const float*)d_in[3];   // [O]
    float* out = (float*)d_out;                   // [B, O, N] fp32

    char* ws = (char*)d_ws;
    float*  xx   = (float*)ws;                                         // 131072 B
    int*    idx  = (int*)(ws + 131072);                                // 2621440 B
    float*  P    = (float*)(ws + 131072 + 2621440);                    // 8 MB
    float*  Dd   = (float*)(ws + 131072 + 2621440 + 8388608);          // 8 MB
    double* sums = (double*)(ws + 131072 + 2621440 + 2 * 8388608);     // 1 KB
    float*  ss   = (float*)(ws + 131072 + 2621440 + 2 * 8388608 + 1024);

    hipMemsetAsync(sums, 0, 128 * sizeof(double), stream);
    xx_kernel<<<dim3(BB * NN / 256), 256, 0, stream>>>(x, xx);
    knn_kernel<<<dim3(NN / KM, BB), 256, 0, stream>>>(x, xx, idx);
    pd_kernel<<<dim3(NN / 256, BB, 2), 256, 0, stream>>>(x, W, P, Dd);
    stats_kernel<<<dim3(BB * NN / 128), 256, 0, stream>>>(P, Dd, idx, sums);
    finalize_kernel<<<1, 64, 0, stream>>>(sums, gamma, beta, ss);
    out_kernel<<<dim3(NN / 64, BB), 256, 0, stream>>>(P, Dd, idx, ss, out);
}

// Round 2
// 1774.992 us; speedup vs baseline: 2.5130x; 2.5130x over previous
//
#include <hip/hip_runtime.h>
#include <cstdint>
#include <cstddef>

#define BB 8
#define CC 64
#define NN 4096
#define OO 64
#define KK 20
#define TWO_C 128

#define LCH 1024   // j-chunk length for knn
#define NCH 4      // number of j-chunks

// ---------------- kernel 0: transpose x[B,C,N] -> xT[B,N,C] ----------------
__global__ __launch_bounds__(256) void transpose_kernel(const float* __restrict__ x,
                                                        float* __restrict__ xT) {
    __shared__ float t[64][65];
    const int b = blockIdx.y;
    const int n0 = blockIdx.x * 64;
    const int ln = threadIdx.x & 63, g = threadIdx.x >> 6;
#pragma unroll
    for (int i = 0; i < 16; ++i) {
        int c = g * 16 + i;
        t[c][ln] = x[((size_t)b * CC + c) * NN + n0 + ln];
    }
    __syncthreads();
#pragma unroll
    for (int i = 0; i < 16; ++i) {
        int nl = g * 16 + i;
        xT[((size_t)b * NN + n0 + nl) * CC + ln] = t[ln][nl];
    }
}

// ---------------- kernel 1: squared norms xx[b,n] ----------------
__global__ __launch_bounds__(256) void xx_kernel(const float* __restrict__ x,
                                                 float* __restrict__ xx) {
    int t = blockIdx.x * 256 + threadIdx.x;  // [0, B*N)
    int b = t >> 12, n = t & (NN - 1);
    const float* xp = x + (size_t)b * CC * NN + n;
    float acc = 0.f;
#pragma unroll
    for (int c = 0; c < CC; ++c) {
        float v = xp[(size_t)c * NN];
        acc += v * v;
    }
    xx[t] = acc;
}

// ---------------- kernel 2a: kNN chunk pass ----------------
// Thread-per-row; j is wave-uniform -> x_j via scalar loads (xT contiguous).
// Keeps sorted top-20 of d' = 2*<xi,xj> - xx_j (ranking-equivalent: -xx_i const).
// Tie-break: (value desc, index asc) — matches lax.top_k.
__global__ __launch_bounds__(256, 2) void knn_chunk_kernel(const float* __restrict__ x,
                                                           const float* __restrict__ xT,
                                                           const float* __restrict__ xx,
                                                           unsigned short* __restrict__ cand) {
    const int b = blockIdx.z;
    const int i = blockIdx.x * 256 + threadIdx.x;
    const int j0 = blockIdx.y * LCH;

    // x_i into registers (coalesced: consecutive threads -> consecutive n)
    float xi[CC];
    const float* xb = x + (size_t)b * CC * NN;
#pragma unroll
    for (int c = 0; c < CC; ++c) xi[c] = xb[(size_t)c * NN + i];

    float lv[KK];
    int   li[KK];
#pragma unroll
    for (int s = 0; s < KK; ++s) { lv[s] = -__builtin_inff(); li[s] = 0x7fffffff; }

    const float* xTb = xT + (size_t)b * NN * CC;
    const float* xxb = xx + b * NN;

    for (int t = 0; t < LCH; ++t) {
        const int jj = __builtin_amdgcn_readfirstlane(j0 + t);
        const float* xj = xTb + (size_t)jj * CC;   // uniform addr -> s_load
        float a0 = 0.f, a1 = 0.f, a2 = 0.f, a3 = 0.f;
#pragma unroll
        for (int c = 0; c < CC; c += 4) {
            a0 = fmaf(xi[c + 0], xj[c + 0], a0);
            a1 = fmaf(xi[c + 1], xj[c + 1], a1);
            a2 = fmaf(xi[c + 2], xj[c + 2], a2);
            a3 = fmaf(xi[c + 3], xj[c + 3], a3);
        }
        float d = 2.f * ((a0 + a1) + (a2 + a3)) - xxb[jj];
        if (d > lv[KK - 1] || (d == lv[KK - 1] && jj < li[KK - 1])) {
            float pv = d; int pi = jj;
#pragma unroll
            for (int s = 0; s < KK; ++s) {
                bool take = (pv > lv[s]) || (pv == lv[s] && pi < li[s]);
                float nv = take ? pv : lv[s];
                int   ni = take ? pi : li[s];
                pv = take ? lv[s] : pv;
                pi = take ? li[s] : pi;
                lv[s] = nv; li[s] = ni;
            }
        }
    }

    unsigned short* cp = cand + (((size_t)b * NN + i) * NCH + blockIdx.y) * KK;
#pragma unroll
    for (int s = 0; s < KK; ++s) cp[s] = (unsigned short)li[s];
}

// ---------------- kernel 2b: merge NCH*20 candidates -> final top-20 ----------------
// Recomputes d' with the SAME fma grouping as the chunk pass (bit-identical).
__global__ __launch_bounds__(256) void knn_merge_kernel(const float* __restrict__ xT,
                                                        const float* __restrict__ xx,
                                                        const unsigned short* __restrict__ cand,
                                                        int* __restrict__ idx_out) {
    const int r = blockIdx.x * 256 + threadIdx.x;  // [0, B*N)
    const int b = r >> 12, i = r & (NN - 1);
    const float* xTb = xT + (size_t)b * NN * CC;
    const float* xxb = xx + b * NN;

    float xi[CC];
    const float* xip = xTb + (size_t)i * CC;
#pragma unroll
    for (int c = 0; c < CC; c += 4) {
        float4 v = *(const float4*)&xip[c];
        xi[c] = v.x; xi[c + 1] = v.y; xi[c + 2] = v.z; xi[c + 3] = v.w;
    }

    float lv[KK];
    int   li[KK];
#pragma unroll
    for (int s = 0; s < KK; ++s) { lv[s] = -__builtin_inff(); li[s] = 0x7fffffff; }

    const unsigned short* cp = cand + (size_t)r * NCH * KK;
    for (int q = 0; q < NCH * KK; ++q) {
        int jj = cp[q];
        const float* xj = xTb + (size_t)jj * CC;
        float a0 = 0.f, a1 = 0.f, a2 = 0.f, a3 = 0.f;
#pragma unroll
        for (int c = 0; c < CC; c += 4) {
            a0 = fmaf(xi[c + 0], xj[c + 0], a0);
            a1 = fmaf(xi[c + 1], xj[c + 1], a1);
            a2 = fmaf(xi[c + 2], xj[c + 2], a2);
            a3 = fmaf(xi[c + 3], xj[c + 3], a3);
        }
        float d = 2.f * ((a0 + a1) + (a2 + a3)) - xxb[jj];
        if (d > lv[KK - 1] || (d == lv[KK - 1] && jj < li[KK - 1])) {
            float pv = d; int pi = jj;
#pragma unroll
            for (int s = 0; s < KK; ++s) {
                bool take = (pv > lv[s]) || (pv == lv[s] && pi < li[s]);
                float nv = take ? pv : lv[s];
                int   ni = take ? pi : li[s];
                pv = take ? lv[s] : pv;
                pi = take ? li[s] : pi;
                lv[s] = nv; li[s] = ni;
            }
        }
    }

    int* op = idx_out + (size_t)r * KK;
#pragma unroll
    for (int s = 0; s < KK; ++s) op[s] = li[s];
}

// ---------------- kernel 3: P = xt*W1^T, D = xt*(W2-W1)^T ----------------
__global__ __launch_bounds__(256) void pd_kernel(const float* __restrict__ x,
                                                 const float* __restrict__ W,
                                                 float* __restrict__ P,
                                                 float* __restrict__ Dd) {
    __shared__ float w1T[CC][32];
    __shared__ float wdT[CC][32];
    const int tid = threadIdx.x;
    const int b = blockIdx.y;
    const int o0 = blockIdx.z * 32;
    for (int e = tid; e < 32 * CC; e += 256) {
        int ol = e >> 6, c = e & 63;
        float w1 = W[(o0 + ol) * TWO_C + c];
        float w2 = W[(o0 + ol) * TWO_C + CC + c];
        w1T[c][ol] = w1;
        wdT[c][ol] = w2 - w1;
    }
    __syncthreads();
    const int n = blockIdx.x * 256 + tid;
    float accp[32], accd[32];
#pragma unroll
    for (int i = 0; i < 32; ++i) { accp[i] = 0.f; accd[i] = 0.f; }
    const float* xp = x + (size_t)b * CC * NN + n;
    for (int c = 0; c < CC; ++c) {
        float xv = xp[(size_t)c * NN];
        const float4* w1r = (const float4*)&w1T[c][0];
        const float4* wdr = (const float4*)&wdT[c][0];
#pragma unroll
        for (int g = 0; g < 8; ++g) {
            float4 aw = w1r[g]; float4 bw = wdr[g];
            accp[4*g+0] += xv * aw.x; accp[4*g+1] += xv * aw.y;
            accp[4*g+2] += xv * aw.z; accp[4*g+3] += xv * aw.w;
            accd[4*g+0] += xv * bw.x; accd[4*g+1] += xv * bw.y;
            accd[4*g+2] += xv * bw.z; accd[4*g+3] += xv * bw.w;
        }
    }
    size_t base = ((size_t)b * NN + n) * OO + o0;
#pragma unroll
    for (int g = 0; g < 8; ++g) {
        *(float4*)&P[base + 4*g]  = make_float4(accp[4*g], accp[4*g+1], accp[4*g+2], accp[4*g+3]);
        *(float4*)&Dd[base + 4*g] = make_float4(accd[4*g], accd[4*g+1], accd[4*g+2], accd[4*g+3]);
    }
}

// ---------------- kernel 4: BN batch stats (sum, sumsq) per channel ----------------
__global__ __launch_bounds__(256) void stats_kernel(const float* __restrict__ P,
                                                    const float* __restrict__ Dd,
                                                    const int* __restrict__ idx,
                                                    double* __restrict__ sums) {
    const int tid = threadIdx.x;
    const int o = tid & 63, g = tid >> 6;
    const int row0 = blockIdx.x * 128;
    double s1 = 0.0, s2 = 0.0;
    for (int i = 0; i < 32; ++i) {
        int row = row0 + g + 4 * i;
        int b = row >> 12;
        float d = Dd[(size_t)row * OO + o];
        const int* ip = idx + (size_t)row * KK;
        const float* Pb = P + ((size_t)b * NN) * OO;
#pragma unroll
        for (int k = 0; k < KK; ++k) {
            int j = ip[k];
            float y = Pb[(size_t)j * OO + o] + d;
            s1 += (double)y;
            s2 += (double)y * (double)y;
        }
    }
    __shared__ double r1[4][64];
    __shared__ double r2[4][64];
    r1[g][o] = s1; r2[g][o] = s2;
    __syncthreads();
    if (g == 0) {
        double a1 = r1[0][o] + r1[1][o] + r1[2][o] + r1[3][o];
        double a2 = r2[0][o] + r2[1][o] + r2[2][o] + r2[3][o];
        atomicAdd(&sums[o], a1);
        atomicAdd(&sums[64 + o], a2);
    }
}

// ---------------- kernel 5: finalize scale/shift ----------------
__global__ void finalize_kernel(const double* __restrict__ sums,
                                const float* __restrict__ gamma,
                                const float* __restrict__ beta,
                                float* __restrict__ ss) {
    int o = threadIdx.x;  // 64 threads
    const double cnt = (double)BB * NN * KK;
    double mean = sums[o] / cnt;
    double var = sums[64 + o] / cnt - mean * mean;
    double rs = 1.0 / sqrt(var + 1e-5);
    double sc = (double)gamma[o] * rs;
    ss[o] = (float)sc;
    ss[64 + o] = (float)((double)beta[o] - mean * sc);
}

// ---------------- kernel 6: gather + BN affine + LeakyReLU + max_k + transpose ----------------
__global__ __launch_bounds__(256) void out_kernel(const float* __restrict__ P,
                                                  const float* __restrict__ Dd,
                                                  const int* __restrict__ idx,
                                                  const float* __restrict__ ss,
                                                  float* __restrict__ out) {
    __shared__ float tile[64][65];
    const int tid = threadIdx.x;
    const int o = tid & 63, g = tid >> 6;
    const int b = blockIdx.y;
    const int n0 = blockIdx.x * 64;
    const float sc = ss[o], sh = ss[64 + o];
    const float* Pb = P + ((size_t)b * NN) * OO;
    for (int i = 0; i < 16; ++i) {
        int nl = g + 4 * i;
        int row = b * NN + n0 + nl;
        float d = Dd[(size_t)row * OO + o];
        const int* ip = idx + (size_t)row * KK;
        float mv = -__builtin_inff();
#pragma unroll
        for (int k = 0; k < KK; ++k) {
            int j = ip[k];
            float y = Pb[(size_t)j * OO + o] + d;
            float t = y * sc + sh;
            t = (t >= 0.f) ? t : 0.2f * t;
            mv = fmaxf(mv, t);
        }
        tile[nl][o] = mv;
    }
    __syncthreads();
    for (int i = 0; i < 16; ++i) {
        int oo = g + 4 * i;
        out[((size_t)b * OO + oo) * NN + n0 + o] = tile[o][oo];
    }
}

// ---------------- launch ----------------
extern "C" void kernel_launch(void* const* d_in, const int* in_sizes, int n_in,
                              void* d_out, int out_size, void* d_ws, size_t ws_size,
                              hipStream_t stream) {
    (void)in_sizes; (void)n_in; (void)out_size; (void)ws_size;
    const float* x     = (const float*)d_in[0];   // [B, C, N]
    const float* W     = (const float*)d_in[1];   // [O, 2C]
    const float* gamma = (const float*)d_in[2];   // [O]
    const float* beta  = (const float*)d_in[3];   // [O]
    float* out = (float*)d_out;                   // [B, O, N] fp32

    // Workspace layout (peak 19.53 MB, same as round 1):
    //   [0,           131072)   xx           (live: knn phase)
    //   [131072,      2752512)  idx          (live: merge -> end)
    //   [2752512,     11141120) xT           (live: knn+merge)   -> reused as P
    //   [11141120,    16384000) cand (u16)   (live: knn->merge)  -> reused as D
    //   P @ 2752512 (8 MB), D @ 11141120 (8 MB)  (written by pd AFTER merge)
    //   [19529728,    19530752) sums, [19530752, ...) ss
    char* ws = (char*)d_ws;
    float*          xx   = (float*)ws;
    int*            idx  = (int*)(ws + 131072);
    float*          xT   = (float*)(ws + 2752512);
    unsigned short* cand = (unsigned short*)(ws + 11141120);
    float*          P    = (float*)(ws + 2752512);
    float*          Dd   = (float*)(ws + 11141120);
    double*         sums = (double*)(ws + 19529728);
    float*          ss   = (float*)(ws + 19530752);

    hipMemsetAsync(sums, 0, 128 * sizeof(double), stream);
    transpose_kernel<<<dim3(NN / 64, BB), 256, 0, stream>>>(x, xT);
    xx_kernel<<<dim3(BB * NN / 256), 256, 0, stream>>>(x, xx);
    knn_chunk_kernel<<<dim3(NN / 256, NCH, BB), 256, 0, stream>>>(x, xT, xx, cand);
    knn_merge_kernel<<<dim3(BB * NN / 256), 256, 0, stream>>>(xT, xx, cand, idx);
    pd_kernel<<<dim3(NN / 256, BB, 2), 256, 0, stream>>>(x, W, P, Dd);
    stats_kernel<<<dim3(BB * NN / 128), 256, 0, stream>>>(P, Dd, idx, sums);
    finalize_kernel<<<1, 64, 0, stream>>>(sums, gamma, beta, ss);
    out_kernel<<<dim3(NN / 64, BB), 256, 0, stream>>>(P, Dd, idx, ss, out);
}

// Round 3
// 1475.194 us; speedup vs baseline: 3.0237x; 1.2032x over previous
//
#include <hip/hip_runtime.h>
#include <cstdint>
#include <cstddef>

#define BB 8
#define CC 64
#define NN 4096
#define OO 64
#define KK 20
#define TWO_C 128

#define LCH 512    // j-chunk length for knn
#define NCH 8      // number of j-chunks

// ---------------- kernel 0: transpose x[B,C,N] -> xT[B,N,C] ----------------
__global__ __launch_bounds__(256) void transpose_kernel(const float* __restrict__ x,
                                                        float* __restrict__ xT) {
    __shared__ float t[64][65];
    const int b = blockIdx.y;
    const int n0 = blockIdx.x * 64;
    const int ln = threadIdx.x & 63, g = threadIdx.x >> 6;
#pragma unroll
    for (int i = 0; i < 16; ++i) {
        int c = g * 16 + i;
        t[c][ln] = x[((size_t)b * CC + c) * NN + n0 + ln];
    }
    __syncthreads();
#pragma unroll
    for (int i = 0; i < 16; ++i) {
        int nl = g * 16 + i;
        xT[((size_t)b * NN + n0 + nl) * CC + ln] = t[ln][nl];
    }
}

// ---------------- kernel 1: squared norms xx[b,n] ----------------
__global__ __launch_bounds__(256) void xx_kernel(const float* __restrict__ x,
                                                 float* __restrict__ xx) {
    int t = blockIdx.x * 256 + threadIdx.x;  // [0, B*N)
    int b = t >> 12, n = t & (NN - 1);
    const float* xp = x + (size_t)b * CC * NN + n;
    float acc = 0.f;
#pragma unroll
    for (int c = 0; c < CC; ++c) {
        float v = xp[(size_t)c * NN];
        acc += v * v;
    }
    xx[t] = acc;
}

// Monotone float->uint map: a > b (float) <=> mu(a) > mu(b) (uint)
__device__ __forceinline__ unsigned int fmap(float d) {
    unsigned int s = __float_as_uint(d);
    return s ^ (unsigned int)(((int)s >> 31) | 0x80000000);
}

// ---------------- kernel 2a: kNN chunk pass ----------------
// Thread-per-row; j is wave-uniform -> x_j via scalar loads (xT contiguous).
// Ranks by d' = 2*<xi,xj> - xx_j (ranking-equivalent: -xx_i const per row).
// Key = (fmap(d') << 32) | ~j  -> value desc, index asc tie-break (lax.top_k).
__global__ __launch_bounds__(256, 3) void knn_chunk_kernel(const float* __restrict__ x,
                                                           const float* __restrict__ xT,
                                                           const float* __restrict__ xx,
                                                           unsigned short* __restrict__ cand) {
    const int b = blockIdx.z;
    const int i = blockIdx.x * 256 + threadIdx.x;
    const int j0 = blockIdx.y * LCH;

    // x_i into registers (coalesced across lanes), then PIN so the compiler
    // cannot sink the loads into the j-loop (round-2 failure: VGPR=76 proved
    // xi was re-loaded from cache on every j iteration).
    float xi[CC];
    const float* xb = x + (size_t)b * CC * NN;
#pragma unroll
    for (int c = 0; c < CC; ++c) xi[c] = xb[(size_t)c * NN + i];
#pragma unroll
    for (int c = 0; c < CC; ++c) asm volatile("" : "+v"(xi[c]));

    unsigned long long L[KK];
#pragma unroll
    for (int s = 0; s < KK; ++s) L[s] = 0ull;

    const float* xTb = xT + (size_t)b * NN * CC;
    const float* xxb = xx + b * NN;

    for (int t = 0; t < LCH; ++t) {
        const int jj = __builtin_amdgcn_readfirstlane(j0 + t);
        const float* xj = xTb + (size_t)jj * CC;   // uniform addr -> s_load
        float a0 = 0.f, a1 = 0.f, a2 = 0.f, a3 = 0.f;
#pragma unroll
        for (int c = 0; c < CC; c += 4) {
            a0 = fmaf(xi[c + 0], xj[c + 0], a0);
            a1 = fmaf(xi[c + 1], xj[c + 1], a1);
            a2 = fmaf(xi[c + 2], xj[c + 2], a2);
            a3 = fmaf(xi[c + 3], xj[c + 3], a3);
        }
        float d = 2.f * ((a0 + a1) + (a2 + a3)) - xxb[jj];
        unsigned long long key = ((unsigned long long)fmap(d) << 32) | (unsigned int)(~jj);
        if (key > L[KK - 1]) {
            unsigned long long p = key;
#pragma unroll
            for (int s = 0; s < KK; ++s) {
                bool take = p > L[s];
                unsigned long long nl = take ? p : L[s];
                p = take ? L[s] : p;
                L[s] = nl;
            }
        }
    }

    // store top-20 neighbor indices (desc by key); j = ~low32(key), fits u16
    unsigned short* cp = cand + (((size_t)b * NN + i) * NCH + blockIdx.y) * KK;
#pragma unroll
    for (int s = 0; s < KK; ++s)
        cp[s] = (unsigned short)(~(unsigned int)L[s] & 0xFFFFu);
}

// ---------------- kernel 2b: merge NCH*20 candidates -> final top-20 ----------------
// 4 threads per row, each re-ranks 2 chunks' 40 candidates (recompute d' with the
// SAME fma grouping -> bit-identical keys), then 4-list pop-max in LDS.
__global__ __launch_bounds__(256, 3) void knn_merge_kernel(const float* __restrict__ xT,
                                                           const float* __restrict__ xx,
                                                           const unsigned short* __restrict__ cand,
                                                           unsigned short* __restrict__ idx_out) {
    __shared__ unsigned long long sh[64][4][KK + 1];
    const int tid = threadIdx.x;
    const int sub = tid & 3, rloc = tid >> 2;
    const int r = blockIdx.x * 64 + rloc;          // [0, B*N)
    const int b = r >> 12, i = r & (NN - 1);
    const float* xTb = xT + (size_t)b * NN * CC;
    const float* xxb = xx + b * NN;

    float xi[CC];
    const float* xip = xTb + (size_t)i * CC;
#pragma unroll
    for (int c = 0; c < CC; c += 4) {
        float4 v = *(const float4*)&xip[c];
        xi[c] = v.x; xi[c + 1] = v.y; xi[c + 2] = v.z; xi[c + 3] = v.w;
    }
#pragma unroll
    for (int c = 0; c < CC; ++c) asm volatile("" : "+v"(xi[c]));

    unsigned long long L[KK];
#pragma unroll
    for (int s = 0; s < KK; ++s) L[s] = 0ull;

    const unsigned short* cp = cand + (size_t)r * (NCH * KK) + sub * (2 * KK);
    for (int q = 0; q < 2 * KK; ++q) {
        int jj = cp[q];
        const float* xj = xTb + (size_t)jj * CC;
        float a0 = 0.f, a1 = 0.f, a2 = 0.f, a3 = 0.f;
#pragma unroll
        for (int c = 0; c < CC; c += 4) {
            a0 = fmaf(xi[c + 0], xj[c + 0], a0);
            a1 = fmaf(xi[c + 1], xj[c + 1], a1);
            a2 = fmaf(xi[c + 2], xj[c + 2], a2);
            a3 = fmaf(xi[c + 3], xj[c + 3], a3);
        }
        float d = 2.f * ((a0 + a1) + (a2 + a3)) - xxb[jj];
        unsigned long long key = ((unsigned long long)fmap(d) << 32) | (unsigned int)(~jj);
        if (key > L[KK - 1]) {
            unsigned long long p = key;
#pragma unroll
            for (int s = 0; s < KK; ++s) {
                bool take = p > L[s];
                unsigned long long nl = take ? p : L[s];
                p = take ? L[s] : p;
                L[s] = nl;
            }
        }
    }

#pragma unroll
    for (int s = 0; s < KK; ++s) sh[rloc][sub][s] = L[s];
    sh[rloc][sub][KK] = 0ull;   // sentinel (below any real key)
    __builtin_amdgcn_wave_barrier();   // 4 row-threads are in the same wave (lockstep)

    if (sub == 0) {
        int h0 = 0, h1 = 0, h2 = 0, h3 = 0;
        unsigned short* op = idx_out + (size_t)r * KK;
        for (int k = 0; k < KK; ++k) {
            unsigned long long k0 = sh[rloc][0][h0];
            unsigned long long k1 = sh[rloc][1][h1];
            unsigned long long k2 = sh[rloc][2][h2];
            unsigned long long k3 = sh[rloc][3][h3];
            unsigned long long best = k0; int src = 0;
            if (k1 > best) { best = k1; src = 1; }
            if (k2 > best) { best = k2; src = 2; }
            if (k3 > best) { best = k3; src = 3; }
            op[k] = (unsigned short)(~(unsigned int)best & 0xFFFFu);
            h0 += (src == 0); h1 += (src == 1); h2 += (src == 2); h3 += (src == 3);
        }
    }
}

// ---------------- kernel 3: P = xt*W1^T, D = xt*(W2-W1)^T ----------------
__global__ __launch_bounds__(256) void pd_kernel(const float* __restrict__ x,
                                                 const float* __restrict__ W,
                                                 float* __restrict__ P,
                                                 float* __restrict__ Dd) {
    __shared__ float w1T[CC][32];
    __shared__ float wdT[CC][32];
    const int tid = threadIdx.x;
    const int b = blockIdx.y;
    const int o0 = blockIdx.z * 32;
    for (int e = tid; e < 32 * CC; e += 256) {
        int ol = e >> 6, c = e & 63;
        float w1 = W[(o0 + ol) * TWO_C + c];
        float w2 = W[(o0 + ol) * TWO_C + CC + c];
        w1T[c][ol] = w1;
        wdT[c][ol] = w2 - w1;
    }
    __syncthreads();
    const int n = blockIdx.x * 256 + tid;
    float accp[32], accd[32];
#pragma unroll
    for (int i = 0; i < 32; ++i) { accp[i] = 0.f; accd[i] = 0.f; }
    const float* xp = x + (size_t)b * CC * NN + n;
    for (int c = 0; c < CC; ++c) {
        float xv = xp[(size_t)c * NN];
        const float4* w1r = (const float4*)&w1T[c][0];
        const float4* wdr = (const float4*)&wdT[c][0];
#pragma unroll
        for (int g = 0; g < 8; ++g) {
            float4 aw = w1r[g]; float4 bw = wdr[g];
            accp[4*g+0] += xv * aw.x; accp[4*g+1] += xv * aw.y;
            accp[4*g+2] += xv * aw.z; accp[4*g+3] += xv * aw.w;
            accd[4*g+0] += xv * bw.x; accd[4*g+1] += xv * bw.y;
            accd[4*g+2] += xv * bw.z; accd[4*g+3] += xv * bw.w;
        }
    }
    size_t base = ((size_t)b * NN + n) * OO + o0;
#pragma unroll
    for (int g = 0; g < 8; ++g) {
        *(float4*)&P[base + 4*g]  = make_float4(accp[4*g], accp[4*g+1], accp[4*g+2], accp[4*g+3]);
        *(float4*)&Dd[base + 4*g] = make_float4(accd[4*g], accd[4*g+1], accd[4*g+2], accd[4*g+3]);
    }
}

// ---------------- kernel 4: BN batch stats (sum, sumsq) per channel ----------------
__global__ __launch_bounds__(256) void stats_kernel(const float* __restrict__ P,
                                                    const float* __restrict__ Dd,
                                                    const unsigned short* __restrict__ idx,
                                                    double* __restrict__ sums) {
    const int tid = threadIdx.x;
    const int o = tid & 63, g = tid >> 6;
    const int row0 = blockIdx.x * 128;
    double s1 = 0.0, s2 = 0.0;
    for (int i = 0; i < 32; ++i) {
        int row = row0 + g + 4 * i;
        int b = row >> 12;
        float d = Dd[(size_t)row * OO + o];
        const unsigned short* ip = idx + (size_t)row * KK;
        const float* Pb = P + ((size_t)b * NN) * OO;
#pragma unroll
        for (int k = 0; k < KK; ++k) {
            int j = ip[k];
            float y = Pb[(size_t)j * OO + o] + d;
            s1 += (double)y;
            s2 += (double)y * (double)y;
        }
    }
    __shared__ double r1[4][64];
    __shared__ double r2[4][64];
    r1[g][o] = s1; r2[g][o] = s2;
    __syncthreads();
    if (g == 0) {
        double a1 = r1[0][o] + r1[1][o] + r1[2][o] + r1[3][o];
        double a2 = r2[0][o] + r2[1][o] + r2[2][o] + r2[3][o];
        atomicAdd(&sums[o], a1);
        atomicAdd(&sums[64 + o], a2);
    }
}

// ---------------- kernel 5: finalize scale/shift ----------------
__global__ void finalize_kernel(const double* __restrict__ sums,
                                const float* __restrict__ gamma,
                                const float* __restrict__ beta,
                                float* __restrict__ ss) {
    int o = threadIdx.x;  // 64 threads
    const double cnt = (double)BB * NN * KK;
    double mean = sums[o] / cnt;
    double var = sums[64 + o] / cnt - mean * mean;
    double rs = 1.0 / sqrt(var + 1e-5);
    double sc = (double)gamma[o] * rs;
    ss[o] = (float)sc;
    ss[64 + o] = (float)((double)beta[o] - mean * sc);
}

// ---------------- kernel 6: gather + BN affine + LeakyReLU + max_k + transpose ----------------
__global__ __launch_bounds__(256) void out_kernel(const float* __restrict__ P,
                                                  const float* __restrict__ Dd,
                                                  const unsigned short* __restrict__ idx,
                                                  const float* __restrict__ ss,
                                                  float* __restrict__ out) {
    __shared__ float tile[64][65];
    const int tid = threadIdx.x;
    const int o = tid & 63, g = tid >> 6;
    const int b = blockIdx.y;
    const int n0 = blockIdx.x * 64;
    const float sc = ss[o], sh = ss[64 + o];
    const float* Pb = P + ((size_t)b * NN) * OO;
    for (int i = 0; i < 16; ++i) {
        int nl = g + 4 * i;
        int row = b * NN + n0 + nl;
        float d = Dd[(size_t)row * OO + o];
        const unsigned short* ip = idx + (size_t)row * KK;
        float mv = -__builtin_inff();
#pragma unroll
        for (int k = 0; k < KK; ++k) {
            int j = ip[k];
            float y = Pb[(size_t)j * OO + o] + d;
            float t = y * sc + sh;
            t = (t >= 0.f) ? t : 0.2f * t;
            mv = fmaxf(mv, t);
        }
        tile[nl][o] = mv;
    }
    __syncthreads();
    for (int i = 0; i < 16; ++i) {
        int oo = g + 4 * i;
        out[((size_t)b * OO + oo) * NN + n0 + o] = tile[o][oo];
    }
}

// ---------------- launch ----------------
extern "C" void kernel_launch(void* const* d_in, const int* in_sizes, int n_in,
                              void* d_out, int out_size, void* d_ws, size_t ws_size,
                              hipStream_t stream) {
    (void)in_sizes; (void)n_in; (void)out_size; (void)ws_size;
    const float* x     = (const float*)d_in[0];   // [B, C, N]
    const float* W     = (const float*)d_in[1];   // [O, 2C]
    const float* gamma = (const float*)d_in[2];   // [O]
    const float* beta  = (const float*)d_in[3];   // [O]
    float* out = (float*)d_out;                   // [B, O, N] fp32

    // Workspace (peak ~20.32 MB):
    //   xx   @ 0         131,072   (live: knn+merge)
    //   xT   @ 131,072   8,388,608 (live: knn+merge)   -> reused as P
    //   cand @ 8,519,680 10,485,760 (live: knn->merge) -> reused as D
    //   idx  @ 19,005,440 1,310,720 u16 (live: merge -> end)
    //   sums @ 20,316,160, ss @ 20,317,184
    char* ws = (char*)d_ws;
    float*          xx   = (float*)ws;
    float*          xT   = (float*)(ws + 131072);
    unsigned short* cand = (unsigned short*)(ws + 8519680);
    unsigned short* idx  = (unsigned short*)(ws + 19005440);
    float*          P    = (float*)(ws + 131072);
    float*          Dd   = (float*)(ws + 8519680);
    double*         sums = (double*)(ws + 20316160);
    float*          ss   = (float*)(ws + 20317184);

    hipMemsetAsync(sums, 0, 128 * sizeof(double), stream);
    transpose_kernel<<<dim3(NN / 64, BB), 256, 0, stream>>>(x, xT);
    xx_kernel<<<dim3(BB * NN / 256), 256, 0, stream>>>(x, xx);
    knn_chunk_kernel<<<dim3(NN / 256, NCH, BB), 256, 0, stream>>>(x, xT, xx, cand);
    knn_merge_kernel<<<dim3(BB * NN / 64), 256, 0, stream>>>(xT, xx, cand, idx);
    pd_kernel<<<dim3(NN / 256, BB, 2), 256, 0, stream>>>(x, W, P, Dd);
    stats_kernel<<<dim3(BB * NN / 128), 256, 0, stream>>>(P, Dd, idx, sums);
    finalize_kernel<<<1, 64, 0, stream>>>(sums, gamma, beta, ss);
    out_kernel<<<dim3(NN / 64, BB), 256, 0, stream>>>(P, Dd, idx, ss, out);
}

// Round 4
// 1468.296 us; speedup vs baseline: 3.0379x; 1.0047x over previous
//
#include <hip/hip_runtime.h>
#include <cstdint>
#include <cstddef>

#define BB 8
#define CC 64
#define NN 4096
#define OO 64
#define KK 20
#define TWO_C 128

#define LCH 512    // j-chunk length for knn
#define NCH 8      // number of j-chunks

typedef float vf4 __attribute__((ext_vector_type(4)));

// ---------------- kernel 0: transpose x[B,C,N] -> xT[B,N,C] ----------------
__global__ __launch_bounds__(256) void transpose_kernel(const float* __restrict__ x,
                                                        float* __restrict__ xT) {
    __shared__ float t[64][65];
    const int b = blockIdx.y;
    const int n0 = blockIdx.x * 64;
    const int ln = threadIdx.x & 63, g = threadIdx.x >> 6;
#pragma unroll
    for (int i = 0; i < 16; ++i) {
        int c = g * 16 + i;
        t[c][ln] = x[((size_t)b * CC + c) * NN + n0 + ln];
    }
    __syncthreads();
#pragma unroll
    for (int i = 0; i < 16; ++i) {
        int nl = g * 16 + i;
        xT[((size_t)b * NN + n0 + nl) * CC + ln] = t[ln][nl];
    }
}

// ---------------- kernel 1: squared norms xx[b,n] ----------------
__global__ __launch_bounds__(256) void xx_kernel(const float* __restrict__ x,
                                                 float* __restrict__ xx) {
    int t = blockIdx.x * 256 + threadIdx.x;  // [0, B*N)
    int b = t >> 12, n = t & (NN - 1);
    const float* xp = x + (size_t)b * CC * NN + n;
    float acc = 0.f;
#pragma unroll
    for (int c = 0; c < CC; ++c) {
        float v = xp[(size_t)c * NN];
        acc += v * v;
    }
    xx[t] = acc;
}

// Monotone float->uint map: a > b (float) <=> mu(a) > mu(b) (uint)
__device__ __forceinline__ unsigned int fmap(float d) {
    unsigned int s = __float_as_uint(d);
    return s ^ (unsigned int)(((int)s >> 31) | 0x80000000);
}

// ---------------- kernel 2a: kNN chunk pass ----------------
// Thread-per-row; j is wave-uniform -> x_j via scalar loads (xT contiguous).
// Ranks by d' = 2*<xi,xj> - xx_j (ranking-equivalent: -xx_i const per row).
// Key = (fmap(d') << 32) | ~j  -> value desc, index asc tie-break (lax.top_k).
// xi is loaded via INLINE-ASM loads: opaque origin -> compiler cannot
// rematerialize them inside the j-loop (rounds 2/3 failure: VGPR=72/76 proved
// xi was re-fetched from cache every iteration; FETCH_SIZE identical).
__global__ __launch_bounds__(256, 3) void knn_chunk_kernel(const float* __restrict__ x,
                                                           const float* __restrict__ xT,
                                                           const float* __restrict__ xx,
                                                           unsigned short* __restrict__ cand) {
    const int b = blockIdx.z;
    const int i = blockIdx.x * 256 + threadIdx.x;
    const int j0 = blockIdx.y * LCH;

    float xi[CC];
    const float* xb = x + (size_t)b * CC * NN;
#pragma unroll
    for (int c = 0; c < CC; ++c) {
        const float* p = xb + (size_t)c * NN + i;   // coalesced across lanes
        asm volatile("global_load_dword %0, %1, off" : "=v"(xi[c]) : "v"(p));
    }
    asm volatile("s_waitcnt vmcnt(0)" ::: "memory");

    unsigned long long L[KK];
#pragma unroll
    for (int s = 0; s < KK; ++s) L[s] = 0ull;

    const float* xTb = xT + (size_t)b * NN * CC;
    const float* xxb = xx + b * NN;

    for (int t = 0; t < LCH; ++t) {
        const int jj = __builtin_amdgcn_readfirstlane(j0 + t);
        const float* xj = xTb + (size_t)jj * CC;   // uniform addr -> s_load
        float a0 = 0.f, a1 = 0.f, a2 = 0.f, a3 = 0.f;
#pragma unroll
        for (int c = 0; c < CC; c += 4) {
            a0 = fmaf(xi[c + 0], xj[c + 0], a0);
            a1 = fmaf(xi[c + 1], xj[c + 1], a1);
            a2 = fmaf(xi[c + 2], xj[c + 2], a2);
            a3 = fmaf(xi[c + 3], xj[c + 3], a3);
        }
        float d = 2.f * ((a0 + a1) + (a2 + a3)) - xxb[jj];
        unsigned long long key = ((unsigned long long)fmap(d) << 32) | (unsigned int)(~jj);
        if (key > L[KK - 1]) {
            unsigned long long p = key;
#pragma unroll
            for (int s = 0; s < KK; ++s) {
                bool take = p > L[s];
                unsigned long long nl = take ? p : L[s];
                p = take ? L[s] : p;
                L[s] = nl;
            }
        }
    }

    // store top-20 neighbor indices (desc by key); j = ~low32(key), fits u16
    unsigned short* cp = cand + (((size_t)b * NN + i) * NCH + blockIdx.y) * KK;
#pragma unroll
    for (int s = 0; s < KK; ++s)
        cp[s] = (unsigned short)(~(unsigned int)L[s] & 0xFFFFu);
}

// ---------------- kernel 2b: merge NCH*20 candidates -> final top-20 ----------------
// 4 threads per row, each re-ranks 2 chunks' 40 candidates (recompute d' with the
// SAME fma grouping -> bit-identical keys), then 4-list pop-max in LDS.
__global__ __launch_bounds__(256, 3) void knn_merge_kernel(const float* __restrict__ xT,
                                                           const float* __restrict__ xx,
                                                           const unsigned short* __restrict__ cand,
                                                           unsigned short* __restrict__ idx_out) {
    __shared__ unsigned long long sh[64][4][KK + 1];
    const int tid = threadIdx.x;
    const int sub = tid & 3, rloc = tid >> 2;
    const int r = blockIdx.x * 64 + rloc;          // [0, B*N)
    const int b = r >> 12, i = r & (NN - 1);
    const float* xTb = xT + (size_t)b * NN * CC;
    const float* xxb = xx + b * NN;

    vf4 xiv[CC / 4];
    const float* xip = xTb + (size_t)i * CC;
#pragma unroll
    for (int c4 = 0; c4 < CC / 4; ++c4) {
        const float* p = xip + 4 * c4;
        asm volatile("global_load_dwordx4 %0, %1, off" : "=v"(xiv[c4]) : "v"(p));
    }
    asm volatile("s_waitcnt vmcnt(0)" ::: "memory");

    unsigned long long L[KK];
#pragma unroll
    for (int s = 0; s < KK; ++s) L[s] = 0ull;

    const unsigned short* cp = cand + (size_t)r * (NCH * KK) + sub * (2 * KK);
    for (int q = 0; q < 2 * KK; ++q) {
        int jj = cp[q];
        const float* xj = xTb + (size_t)jj * CC;
        float a0 = 0.f, a1 = 0.f, a2 = 0.f, a3 = 0.f;
#pragma unroll
        for (int c4 = 0; c4 < CC / 4; ++c4) {
            a0 = fmaf(xiv[c4].x, xj[4 * c4 + 0], a0);
            a1 = fmaf(xiv[c4].y, xj[4 * c4 + 1], a1);
            a2 = fmaf(xiv[c4].z, xj[4 * c4 + 2], a2);
            a3 = fmaf(xiv[c4].w, xj[4 * c4 + 3], a3);
        }
        float d = 2.f * ((a0 + a1) + (a2 + a3)) - xxb[jj];
        unsigned long long key = ((unsigned long long)fmap(d) << 32) | (unsigned int)(~jj);
        if (key > L[KK - 1]) {
            unsigned long long p = key;
#pragma unroll
            for (int s = 0; s < KK; ++s) {
                bool take = p > L[s];
                unsigned long long nl = take ? p : L[s];
                p = take ? L[s] : p;
                L[s] = nl;
            }
        }
    }

#pragma unroll
    for (int s = 0; s < KK; ++s) sh[rloc][sub][s] = L[s];
    sh[rloc][sub][KK] = 0ull;   // sentinel (below any real key)
    __builtin_amdgcn_wave_barrier();   // 4 row-threads are in the same wave (lockstep)

    if (sub == 0) {
        int h0 = 0, h1 = 0, h2 = 0, h3 = 0;
        unsigned short* op = idx_out + (size_t)r * KK;
        for (int k = 0; k < KK; ++k) {
            unsigned long long k0 = sh[rloc][0][h0];
            unsigned long long k1 = sh[rloc][1][h1];
            unsigned long long k2 = sh[rloc][2][h2];
            unsigned long long k3 = sh[rloc][3][h3];
            unsigned long long best = k0; int src = 0;
            if (k1 > best) { best = k1; src = 1; }
            if (k2 > best) { best = k2; src = 2; }
            if (k3 > best) { best = k3; src = 3; }
            op[k] = (unsigned short)(~(unsigned int)best & 0xFFFFu);
            h0 += (src == 0); h1 += (src == 1); h2 += (src == 2); h3 += (src == 3);
        }
    }
}

// ---------------- kernel 3: P = xt*W1^T, D = xt*(W2-W1)^T ----------------
__global__ __launch_bounds__(256) void pd_kernel(const float* __restrict__ x,
                                                 const float* __restrict__ W,
                                                 float* __restrict__ P,
                                                 float* __restrict__ Dd) {
    __shared__ float w1T[CC][32];
    __shared__ float wdT[CC][32];
    const int tid = threadIdx.x;
    const int b = blockIdx.y;
    const int o0 = blockIdx.z * 32;
    for (int e = tid; e < 32 * CC; e += 256) {
        int ol = e >> 6, c = e & 63;
        float w1 = W[(o0 + ol) * TWO_C + c];
        float w2 = W[(o0 + ol) * TWO_C + CC + c];
        w1T[c][ol] = w1;
        wdT[c][ol] = w2 - w1;
    }
    __syncthreads();
    const int n = blockIdx.x * 256 + tid;
    float accp[32], accd[32];
#pragma unroll
    for (int i = 0; i < 32; ++i) { accp[i] = 0.f; accd[i] = 0.f; }
    const float* xp = x + (size_t)b * CC * NN + n;
    for (int c = 0; c < CC; ++c) {
        float xv = xp[(size_t)c * NN];
        const float4* w1r = (const float4*)&w1T[c][0];
        const float4* wdr = (const float4*)&wdT[c][0];
#pragma unroll
        for (int g = 0; g < 8; ++g) {
            float4 aw = w1r[g]; float4 bw = wdr[g];
            accp[4*g+0] += xv * aw.x; accp[4*g+1] += xv * aw.y;
            accp[4*g+2] += xv * aw.z; accp[4*g+3] += xv * aw.w;
            accd[4*g+0] += xv * bw.x; accd[4*g+1] += xv * bw.y;
            accd[4*g+2] += xv * bw.z; accd[4*g+3] += xv * bw.w;
        }
    }
    size_t base = ((size_t)b * NN + n) * OO + o0;
#pragma unroll
    for (int g = 0; g < 8; ++g) {
        *(float4*)&P[base + 4*g]  = make_float4(accp[4*g], accp[4*g+1], accp[4*g+2], accp[4*g+3]);
        *(float4*)&Dd[base + 4*g] = make_float4(accd[4*g], accd[4*g+1], accd[4*g+2], accd[4*g+3]);
    }
}

// ---------------- kernel 4: BN batch stats (sum, sumsq) per channel ----------------
__global__ __launch_bounds__(256) void stats_kernel(const float* __restrict__ P,
                                                    const float* __restrict__ Dd,
                                                    const unsigned short* __restrict__ idx,
                                                    double* __restrict__ sums) {
    const int tid = threadIdx.x;
    const int o = tid & 63, g = tid >> 6;
    const int row0 = blockIdx.x * 128;
    double s1 = 0.0, s2 = 0.0;
    for (int i = 0; i < 32; ++i) {
        int row = row0 + g + 4 * i;
        int b = row >> 12;
        float d = Dd[(size_t)row * OO + o];
        const unsigned short* ip = idx + (size_t)row * KK;
        const float* Pb = P + ((size_t)b * NN) * OO;
#pragma unroll
        for (int k = 0; k < KK; ++k) {
            int j = ip[k];
            float y = Pb[(size_t)j * OO + o] + d;
            s1 += (double)y;
            s2 += (double)y * (double)y;
        }
    }
    __shared__ double r1[4][64];
    __shared__ double r2[4][64];
    r1[g][o] = s1; r2[g][o] = s2;
    __syncthreads();
    if (g == 0) {
        double a1 = r1[0][o] + r1[1][o] + r1[2][o] + r1[3][o];
        double a2 = r2[0][o] + r2[1][o] + r2[2][o] + r2[3][o];
        atomicAdd(&sums[o], a1);
        atomicAdd(&sums[64 + o], a2);
    }
}

// ---------------- kernel 5: finalize scale/shift ----------------
__global__ void finalize_kernel(const double* __restrict__ sums,
                                const float* __restrict__ gamma,
                                const float* __restrict__ beta,
                                float* __restrict__ ss) {
    int o = threadIdx.x;  // 64 threads
    const double cnt = (double)BB * NN * KK;
    double mean = sums[o] / cnt;
    double var = sums[64 + o] / cnt - mean * mean;
    double rs = 1.0 / sqrt(var + 1e-5);
    double sc = (double)gamma[o] * rs;
    ss[o] = (float)sc;
    ss[64 + o] = (float)((double)beta[o] - mean * sc);
}

// ---------------- kernel 6: gather + BN affine + LeakyReLU + max_k + transpose ----------------
__global__ __launch_bounds__(256) void out_kernel(const float* __restrict__ P,
                                                  const float* __restrict__ Dd,
                                                  const unsigned short* __restrict__ idx,
                                                  const float* __restrict__ ss,
                                                  float* __restrict__ out) {
    __shared__ float tile[64][65];
    const int tid = threadIdx.x;
    const int o = tid & 63, g = tid >> 6;
    const int b = blockIdx.y;
    const int n0 = blockIdx.x * 64;
    const float sc = ss[o], sh = ss[64 + o];
    const float* Pb = P + ((size_t)b * NN) * OO;
    for (int i = 0; i < 16; ++i) {
        int nl = g + 4 * i;
        int row = b * NN + n0 + nl;
        float d = Dd[(size_t)row * OO + o];
        const unsigned short* ip = idx + (size_t)row * KK;
        float mv = -__builtin_inff();
#pragma unroll
        for (int k = 0; k < KK; ++k) {
            int j = ip[k];
            float y = Pb[(size_t)j * OO + o] + d;
            float t = y * sc + sh;
            t = (t >= 0.f) ? t : 0.2f * t;
            mv = fmaxf(mv, t);
        }
        tile[nl][o] = mv;
    }
    __syncthreads();
    for (int i = 0; i < 16; ++i) {
        int oo = g + 4 * i;
        out[((size_t)b * OO + oo) * NN + n0 + o] = tile[o][oo];
    }
}

// ---------------- launch ----------------
extern "C" void kernel_launch(void* const* d_in, const int* in_sizes, int n_in,
                              void* d_out, int out_size, void* d_ws, size_t ws_size,
                              hipStream_t stream) {
    (void)in_sizes; (void)n_in; (void)out_size; (void)ws_size;
    const float* x     = (const float*)d_in[0];   // [B, C, N]
    const float* W     = (const float*)d_in[1];   // [O, 2C]
    const float* gamma = (const float*)d_in[2];   // [O]
    const float* beta  = (const float*)d_in[3];   // [O]
    float* out = (float*)d_out;                   // [B, O, N] fp32

    // Workspace (peak ~20.32 MB):
    //   xx   @ 0         131,072   (live: knn+merge)
    //   xT   @ 131,072   8,388,608 (live: knn+merge)   -> reused as P
    //   cand @ 8,519,680 10,485,760 (live: knn->merge) -> reused as D
    //   idx  @ 19,005,440 1,310,720 u16 (live: merge -> end)
    //   sums @ 20,316,160, ss @ 20,317,184
    char* ws = (char*)d_ws;
    float*          xx   = (float*)ws;
    float*          xT   = (float*)(ws + 131072);
    unsigned short* cand = (unsigned short*)(ws + 8519680);
    unsigned short* idx  = (unsigned short*)(ws + 19005440);
    float*          P    = (float*)(ws + 131072);
    float*          Dd   = (float*)(ws + 8519680);
    double*         sums = (double*)(ws + 20316160);
    float*          ss   = (float*)(ws + 20317184);

    hipMemsetAsync(sums, 0, 128 * sizeof(double), stream);
    transpose_kernel<<<dim3(NN / 64, BB), 256, 0, stream>>>(x, xT);
    xx_kernel<<<dim3(BB * NN / 256), 256, 0, stream>>>(x, xx);
    knn_chunk_kernel<<<dim3(NN / 256, NCH, BB), 256, 0, stream>>>(x, xT, xx, cand);
    knn_merge_kernel<<<dim3(BB * NN / 64), 256, 0, stream>>>(xT, xx, cand, idx);
    pd_kernel<<<dim3(NN / 256, BB, 2), 256, 0, stream>>>(x, W, P, Dd);
    stats_kernel<<<dim3(BB * NN / 128), 256, 0, stream>>>(P, Dd, idx, sums);
    finalize_kernel<<<1, 64, 0, stream>>>(sums, gamma, beta, ss);
    out_kernel<<<dim3(NN / 64, BB), 256, 0, stream>>>(P, Dd, idx, ss, out);
}

// Round 5
// 1200.702 us; speedup vs baseline: 3.7150x; 1.2229x over previous
//
#include <hip/hip_runtime.h>
#include <cstdint>
#include <cstddef>

#define BB 8
#define CC 64
#define NN 4096
#define OO 64
#define KK 20
#define TWO_C 128

#define LCH 512    // j-chunk length for knn
#define NCH 8      // number of j-chunks

typedef float vf4 __attribute__((ext_vector_type(4)));

// ---------------- kernel 0: transpose x[B,C,N] -> xT[B,N,C] ----------------
__global__ __launch_bounds__(256) void transpose_kernel(const float* __restrict__ x,
                                                        float* __restrict__ xT) {
    __shared__ float t[64][65];
    const int b = blockIdx.y;
    const int n0 = blockIdx.x * 64;
    const int ln = threadIdx.x & 63, g = threadIdx.x >> 6;
#pragma unroll
    for (int i = 0; i < 16; ++i) {
        int c = g * 16 + i;
        t[c][ln] = x[((size_t)b * CC + c) * NN + n0 + ln];
    }
    __syncthreads();
#pragma unroll
    for (int i = 0; i < 16; ++i) {
        int nl = g * 16 + i;
        xT[((size_t)b * NN + n0 + nl) * CC + ln] = t[ln][nl];
    }
}

// ---------------- kernel 1: squared norms xx[b,n] ----------------
__global__ __launch_bounds__(256) void xx_kernel(const float* __restrict__ x,
                                                 float* __restrict__ xx) {
    int t = blockIdx.x * 256 + threadIdx.x;  // [0, B*N)
    int b = t >> 12, n = t & (NN - 1);
    const float* xp = x + (size_t)b * CC * NN + n;
    float acc = 0.f;
#pragma unroll
    for (int c = 0; c < CC; ++c) {
        float v = xp[(size_t)c * NN];
        acc += v * v;
    }
    xx[t] = acc;
}

// Monotone float->uint map: a > b (float) <=> mu(a) > mu(b) (uint)
__device__ __forceinline__ unsigned int fmap(float d) {
    unsigned int s = __float_as_uint(d);
    return s ^ (unsigned int)(((int)s >> 31) | 0x80000000);
}

// ---------------- kernel 2a: kNN chunk pass (JT=4 j-group) ----------------
// Thread-per-row; j wave-uniform -> xj via scalar loads. JT=4: each xi[c]
// reload (L1-resident; the compiler refuses to keep xi in VGPRs — rounds 2-4)
// is amortized over 4 j's, and the 4 accumulator chains give 4x ILP.
// Accumulation grouping per j: a[c&3] sub-chains, d = 2*((a0+a1)+(a2+a3))-xx_j
// == EXACTLY the merge kernel's expression -> bit-identical keys.
// Key = (fmap(d) << 32) | ~j  -> value desc, index asc tie-break (lax.top_k).
__global__ __launch_bounds__(256, 4) void knn_chunk_kernel(const float* __restrict__ x,
                                                           const float* __restrict__ xT,
                                                           const float* __restrict__ xx,
                                                           unsigned short* __restrict__ cand) {
    const int b = blockIdx.z;
    const int i = blockIdx.x * 256 + threadIdx.x;
    const int j0 = blockIdx.y * LCH;

    const float* xb  = x + (size_t)b * CC * NN;   // x[c][n] column layout
    const float* xTb = xT + (size_t)b * NN * CC;  // xT[n][c] row layout
    const float* xxb = xx + b * NN;

    unsigned long long L[KK];
#pragma unroll
    for (int s = 0; s < KK; ++s) L[s] = 0ull;

    for (int t = 0; t < LCH; t += 4) {
        const int jj = __builtin_amdgcn_readfirstlane(j0 + t);
        const float* xj0 = xTb + (size_t)(jj + 0) * CC;  // uniform -> s_load
        const float* xj1 = xTb + (size_t)(jj + 1) * CC;
        const float* xj2 = xTb + (size_t)(jj + 2) * CC;
        const float* xj3 = xTb + (size_t)(jj + 3) * CC;

        float a[4][4];
#pragma unroll
        for (int q = 0; q < 4; ++q)
#pragma unroll
            for (int s = 0; s < 4; ++s) a[q][s] = 0.f;

#pragma unroll
        for (int c = 0; c < CC; ++c) {
            float xv = xb[(size_t)c * NN + i];   // one reload feeds 4 j's
            a[0][c & 3] = fmaf(xv, xj0[c], a[0][c & 3]);
            a[1][c & 3] = fmaf(xv, xj1[c], a[1][c & 3]);
            a[2][c & 3] = fmaf(xv, xj2[c], a[2][c & 3]);
            a[3][c & 3] = fmaf(xv, xj3[c], a[3][c & 3]);
        }

#pragma unroll
        for (int q = 0; q < 4; ++q) {
            float d = 2.f * ((a[q][0] + a[q][1]) + (a[q][2] + a[q][3])) - xxb[jj + q];
            unsigned long long key =
                ((unsigned long long)fmap(d) << 32) | (unsigned int)(~(jj + q));
            if (key > L[KK - 1]) {
                unsigned long long p = key;
#pragma unroll
                for (int s = 0; s < KK; ++s) {
                    bool take = p > L[s];
                    unsigned long long nl = take ? p : L[s];
                    p = take ? L[s] : p;
                    L[s] = nl;
                }
            }
        }
    }

    // store top-20 neighbor indices (desc by key); j = ~low32(key), fits u16
    unsigned short* cp = cand + (((size_t)b * NN + i) * NCH + blockIdx.y) * KK;
#pragma unroll
    for (int s = 0; s < KK; ++s)
        cp[s] = (unsigned short)(~(unsigned int)L[s] & 0xFFFFu);
}

// ---------------- kernel 2b: merge NCH*20 candidates -> final top-20 ----------------
// 4 threads per row, each re-ranks 2 chunks' 40 candidates (recompute d' with the
// SAME fma grouping -> bit-identical keys), then 4-list pop-max in LDS.
__global__ __launch_bounds__(256, 3) void knn_merge_kernel(const float* __restrict__ xT,
                                                           const float* __restrict__ xx,
                                                           const unsigned short* __restrict__ cand,
                                                           unsigned short* __restrict__ idx_out) {
    __shared__ unsigned long long sh[64][4][KK + 1];
    const int tid = threadIdx.x;
    const int sub = tid & 3, rloc = tid >> 2;
    const int r = blockIdx.x * 64 + rloc;          // [0, B*N)
    const int b = r >> 12, i = r & (NN - 1);
    const float* xTb = xT + (size_t)b * NN * CC;
    const float* xxb = xx + b * NN;

    vf4 xiv[CC / 4];
    const float* xip = xTb + (size_t)i * CC;
#pragma unroll
    for (int c4 = 0; c4 < CC / 4; ++c4) {
        const float* p = xip + 4 * c4;
        asm volatile("global_load_dwordx4 %0, %1, off" : "=v"(xiv[c4]) : "v"(p));
    }
    asm volatile("s_waitcnt vmcnt(0)" ::: "memory");

    unsigned long long L[KK];
#pragma unroll
    for (int s = 0; s < KK; ++s) L[s] = 0ull;

    const unsigned short* cp = cand + (size_t)r * (NCH * KK) + sub * (2 * KK);
    for (int q = 0; q < 2 * KK; ++q) {
        int jj = cp[q];
        const float* xj = xTb + (size_t)jj * CC;
        float a0 = 0.f, a1 = 0.f, a2 = 0.f, a3 = 0.f;
#pragma unroll
        for (int c4 = 0; c4 < CC / 4; ++c4) {
            a0 = fmaf(xiv[c4].x, xj[4 * c4 + 0], a0);
            a1 = fmaf(xiv[c4].y, xj[4 * c4 + 1], a1);
            a2 = fmaf(xiv[c4].z, xj[4 * c4 + 2], a2);
            a3 = fmaf(xiv[c4].w, xj[4 * c4 + 3], a3);
        }
        float d = 2.f * ((a0 + a1) + (a2 + a3)) - xxb[jj];
        unsigned long long key = ((unsigned long long)fmap(d) << 32) | (unsigned int)(~jj);
        if (key > L[KK - 1]) {
            unsigned long long p = key;
#pragma unroll
            for (int s = 0; s < KK; ++s) {
                bool take = p > L[s];
                unsigned long long nl = take ? p : L[s];
                p = take ? L[s] : p;
                L[s] = nl;
            }
        }
    }

#pragma unroll
    for (int s = 0; s < KK; ++s) sh[rloc][sub][s] = L[s];
    sh[rloc][sub][KK] = 0ull;   // sentinel (below any real key)
    __builtin_amdgcn_wave_barrier();   // 4 row-threads are in the same wave (lockstep)

    if (sub == 0) {
        int h0 = 0, h1 = 0, h2 = 0, h3 = 0;
        unsigned short* op = idx_out + (size_t)r * KK;
        for (int k = 0; k < KK; ++k) {
            unsigned long long k0 = sh[rloc][0][h0];
            unsigned long long k1 = sh[rloc][1][h1];
            unsigned long long k2 = sh[rloc][2][h2];
            unsigned long long k3 = sh[rloc][3][h3];
            unsigned long long best = k0; int src = 0;
            if (k1 > best) { best = k1; src = 1; }
            if (k2 > best) { best = k2; src = 2; }
            if (k3 > best) { best = k3; src = 3; }
            op[k] = (unsigned short)(~(unsigned int)best & 0xFFFFu);
            h0 += (src == 0); h1 += (src == 1); h2 += (src == 2); h3 += (src == 3);
        }
    }
}

// ---------------- kernel 3: P = xt*W1^T, D = xt*(W2-W1)^T ----------------
__global__ __launch_bounds__(256) void pd_kernel(const float* __restrict__ x,
                                                 const float* __restrict__ W,
                                                 float* __restrict__ P,
                                                 float* __restrict__ Dd) {
    __shared__ float w1T[CC][32];
    __shared__ float wdT[CC][32];
    const int tid = threadIdx.x;
    const int b = blockIdx.y;
    const int o0 = blockIdx.z * 32;
    for (int e = tid; e < 32 * CC; e += 256) {
        int ol = e >> 6, c = e & 63;
        float w1 = W[(o0 + ol) * TWO_C + c];
        float w2 = W[(o0 + ol) * TWO_C + CC + c];
        w1T[c][ol] = w1;
        wdT[c][ol] = w2 - w1;
    }
    __syncthreads();
    const int n = blockIdx.x * 256 + tid;
    float accp[32], accd[32];
#pragma unroll
    for (int i = 0; i < 32; ++i) { accp[i] = 0.f; accd[i] = 0.f; }
    const float* xp = x + (size_t)b * CC * NN + n;
    for (int c = 0; c < CC; ++c) {
        float xv = xp[(size_t)c * NN];
        const float4* w1r = (const float4*)&w1T[c][0];
        const float4* wdr = (const float4*)&wdT[c][0];
#pragma unroll
        for (int g = 0; g < 8; ++g) {
            float4 aw = w1r[g]; float4 bw = wdr[g];
            accp[4*g+0] += xv * aw.x; accp[4*g+1] += xv * aw.y;
            accp[4*g+2] += xv * aw.z; accp[4*g+3] += xv * aw.w;
            accd[4*g+0] += xv * bw.x; accd[4*g+1] += xv * bw.y;
            accd[4*g+2] += xv * bw.z; accd[4*g+3] += xv * bw.w;
        }
    }
    size_t base = ((size_t)b * NN + n) * OO + o0;
#pragma unroll
    for (int g = 0; g < 8; ++g) {
        *(float4*)&P[base + 4*g]  = make_float4(accp[4*g], accp[4*g+1], accp[4*g+2], accp[4*g+3]);
        *(float4*)&Dd[base + 4*g] = make_float4(accd[4*g], accd[4*g+1], accd[4*g+2], accd[4*g+3]);
    }
}

// ---------------- kernel 4: BN batch stats (sum, sumsq) per channel ----------------
__global__ __launch_bounds__(256) void stats_kernel(const float* __restrict__ P,
                                                    const float* __restrict__ Dd,
                                                    const unsigned short* __restrict__ idx,
                                                    double* __restrict__ sums) {
    const int tid = threadIdx.x;
    const int o = tid & 63, g = tid >> 6;
    const int row0 = blockIdx.x * 128;
    double s1 = 0.0, s2 = 0.0;
    for (int i = 0; i < 32; ++i) {
        int row = row0 + g + 4 * i;
        int b = row >> 12;
        float d = Dd[(size_t)row * OO + o];
        const unsigned short* ip = idx + (size_t)row * KK;
        const float* Pb = P + ((size_t)b * NN) * OO;
#pragma unroll
        for (int k = 0; k < KK; ++k) {
            int j = ip[k];
            float y = Pb[(size_t)j * OO + o] + d;
            s1 += (double)y;
            s2 += (double)y * (double)y;
        }
    }
    __shared__ double r1[4][64];
    __shared__ double r2[4][64];
    r1[g][o] = s1; r2[g][o] = s2;
    __syncthreads();
    if (g == 0) {
        double a1 = r1[0][o] + r1[1][o] + r1[2][o] + r1[3][o];
        double a2 = r2[0][o] + r2[1][o] + r2[2][o] + r2[3][o];
        atomicAdd(&sums[o], a1);
        atomicAdd(&sums[64 + o], a2);
    }
}

// ---------------- kernel 5: finalize scale/shift ----------------
__global__ void finalize_kernel(const double* __restrict__ sums,
                                const float* __restrict__ gamma,
                                const float* __restrict__ beta,
                                float* __restrict__ ss) {
    int o = threadIdx.x;  // 64 threads
    const double cnt = (double)BB * NN * KK;
    double mean = sums[o] / cnt;
    double var = sums[64 + o] / cnt - mean * mean;
    double rs = 1.0 / sqrt(var + 1e-5);
    double sc = (double)gamma[o] * rs;
    ss[o] = (float)sc;
    ss[64 + o] = (float)((double)beta[o] - mean * sc);
}

// ---------------- kernel 6: gather + BN affine + LeakyReLU + max_k + transpose ----------------
__global__ __launch_bounds__(256) void out_kernel(const float* __restrict__ P,
                                                  const float* __restrict__ Dd,
                                                  const unsigned short* __restrict__ idx,
                                                  const float* __restrict__ ss,
                                                  float* __restrict__ out) {
    __shared__ float tile[64][65];
    const int tid = threadIdx.x;
    const int o = tid & 63, g = tid >> 6;
    const int b = blockIdx.y;
    const int n0 = blockIdx.x * 64;
    const float sc = ss[o], sh = ss[64 + o];
    const float* Pb = P + ((size_t)b * NN) * OO;
    for (int i = 0; i < 16; ++i) {
        int nl = g + 4 * i;
        int row = b * NN + n0 + nl;
        float d = Dd[(size_t)row * OO + o];
        const unsigned short* ip = idx + (size_t)row * KK;
        float mv = -__builtin_inff();
#pragma unroll
        for (int k = 0; k < KK; ++k) {
            int j = ip[k];
            float y = Pb[(size_t)j * OO + o] + d;
            float t = y * sc + sh;
            t = (t >= 0.f) ? t : 0.2f * t;
            mv = fmaxf(mv, t);
        }
        tile[nl][o] = mv;
    }
    __syncthreads();
    for (int i = 0; i < 16; ++i) {
        int oo = g + 4 * i;
        out[((size_t)b * OO + oo) * NN + n0 + o] = tile[o][oo];
    }
}

// ---------------- launch ----------------
extern "C" void kernel_launch(void* const* d_in, const int* in_sizes, int n_in,
                              void* d_out, int out_size, void* d_ws, size_t ws_size,
                              hipStream_t stream) {
    (void)in_sizes; (void)n_in; (void)out_size; (void)ws_size;
    const float* x     = (const float*)d_in[0];   // [B, C, N]
    const float* W     = (const float*)d_in[1];   // [O, 2C]
    const float* gamma = (const float*)d_in[2];   // [O]
    const float* beta  = (const float*)d_in[3];   // [O]
    float* out = (float*)d_out;                   // [B, O, N] fp32

    // Workspace (peak ~20.32 MB):
    //   xx   @ 0         131,072   (live: knn+merge)
    //   xT   @ 131,072   8,388,608 (live: knn+merge)   -> reused as P
    //   cand @ 8,519,680 10,485,760 (live: knn->merge) -> reused as D
    //   idx  @ 19,005,440 1,310,720 u16 (live: merge -> end)
    //   sums @ 20,316,160, ss @ 20,317,184
    char* ws = (char*)d_ws;
    float*          xx   = (float*)ws;
    float*          xT   = (float*)(ws + 131072);
    unsigned short* cand = (unsigned short*)(ws + 8519680);
    unsigned short* idx  = (unsigned short*)(ws + 19005440);
    float*          P    = (float*)(ws + 131072);
    float*          Dd   = (float*)(ws + 8519680);
    double*         sums = (double*)(ws + 20316160);
    float*          ss   = (float*)(ws + 20317184);

    hipMemsetAsync(sums, 0, 128 * sizeof(double), stream);
    transpose_kernel<<<dim3(NN / 64, BB), 256, 0, stream>>>(x, xT);
    xx_kernel<<<dim3(BB * NN / 256), 256, 0, stream>>>(x, xx);
    knn_chunk_kernel<<<dim3(NN / 256, NCH, BB), 256, 0, stream>>>(x, xT, xx, cand);
    knn_merge_kernel<<<dim3(BB * NN / 64), 256, 0, stream>>>(xT, xx, cand, idx);
    pd_kernel<<<dim3(NN / 256, BB, 2), 256, 0, stream>>>(x, W, P, Dd);
    stats_kernel<<<dim3(BB * NN / 128), 256, 0, stream>>>(P, Dd, idx, sums);
    finalize_kernel<<<1, 64, 0, stream>>>(sums, gamma, beta, ss);
    out_kernel<<<dim3(NN / 64, BB), 256, 0, stream>>>(P, Dd, idx, ss, out);
}